// Round 14
// baseline (356.238 us; speedup 1.0000x reference)
//
#include <hip/hip_runtime.h>

#define BATCH 256
#define DD 15
#define HH 63
#define WW 126
#define OD 3
#define OH 13
#define OWI 26
#define SPAT (DD*HH*WW)    // 119070
#define HWSZ (HH*WW)       // 7938
#define NBLK (OD*OH*OWI)   // 1014
#define IJB  (OH*OWI)      // 338 blocks per i-slab
#define WEXP_D (65*130)    // 8450 floats per d-plane (row hp1 in [0,65))
#define NWEXP (DD*WEXP_D)  // 126750
#define NGRP 16            // row groups per WG (2 per wave)
#define NROWS (5*HH)       // 315 rows per i-slab

typedef float f32x4 __attribute__((ext_vector_type(4)));   // native vec for nontemporal store

// ---------------------------------------------------------------------------
// prep: Wexp[d][hp1][wp] = W * land (0 for padding / OOB); lv[blk] =
// sum(land*vol) over block; tbl[r] = u16 block id for the upsample writer.
// ---------------------------------------------------------------------------
__global__ __launch_bounds__(256)
void prep_kernel(const float* __restrict__ W, const float* __restrict__ land,
                 const float* __restrict__ vols,
                 float* __restrict__ Wexp, float* __restrict__ lv,
                 unsigned short* __restrict__ tbl) {
    int idx = blockIdx.x * 256 + threadIdx.x;
    if (idx < NWEXP) {
        int d   = idx / WEXP_D;
        int rem = idx - d * WEXP_D;
        int hp1 = rem / 130;
        int wp  = rem - hp1 * 130;
        float val = 0.f;
        if (hp1 >= 1 && hp1 <= HH && wp >= 2 && wp < 128) {
            int i = d / 5, p = d - 5 * i;
            int h = hp1 - 1, w = wp - 2;
            int j = hp1 / 5, q = hp1 - 5 * j;
            int k = wp / 5,  r = wp - 5 * k;
            int blk = (i * OH + j) * OWI + k;
            val = W[blk * 125 + p * 25 + q * 5 + r] * land[(d * HH + h) * WW + w];
        }
        Wexp[idx] = val;
    } else if (idx < NWEXP + NBLK) {
        int blk = idx - NWEXP;
        int ij = blk / OWI, k = blk - ij * OWI;
        int i  = ij / OH,   j = ij - i * OH;
        float s = 0.f;
        for (int p = 0; p < 5; ++p) {
            int d = i * 5 + p;
            for (int q = 0; q < 5; ++q) {
                int h = j * 5 + q - 1;
                if ((unsigned)h >= (unsigned)HH) continue;
                int base = (d * HH + h) * WW;
                for (int r = 0; r < 5; ++r) {
                    int w = k * 5 + r - 2;
                    if ((unsigned)w < (unsigned)WW)
                        s += land[base + w] * vols[base + w];
                }
            }
        }
        lv[blk] = s;
    } else if (idx < NWEXP + NBLK + SPAT) {
        int r  = idx - NWEXP - NBLK;
        int d  = r / HWSZ;
        int r2 = r - d * HWSZ;
        int h  = r2 / WW;
        int w  = r2 - h * WW;
        tbl[r] = (unsigned short)(((d / 5) * OH + (h + 1) / 5) * OWI + (w + 2) / 5);
    }
}

// ---------------------------------------------------------------------------
// conv: WG = (b, i-slab), 8 waves -> 16 half-wave groups. Group g owns the
// CONTIGUOUS row span [20g, min(20g+20, 315)) and processes 4 rows per
// iteration with INDEPENDENT accumulators miv[0..3]: 60 independent loads
// and 4 independent FMA chains per iteration -> deep MLP. No barrier in loop.
// ---------------------------------------------------------------------------
__global__ __launch_bounds__(512)
void conv_kernel(const float* __restrict__ x, const float* __restrict__ vols,
                 const float* __restrict__ Wexp, const float* __restrict__ lv,
                 const float* __restrict__ bias, float* __restrict__ y_small,
                 double* __restrict__ mass_in, double* __restrict__ mass_out) {
    __shared__ float acc[NGRP * IJB];   // [group][j*26+k]  = 21632 B
    __shared__ float redmi[8];
    __shared__ float redmo[8];
    const int tid  = threadIdx.x;
    const int wv   = tid >> 6;
    const int lane = tid & 63;
    const int lg   = lane & 31;                 // lane within half-wave
    const int g    = wv * 2 + (lane >> 5);      // row group 0..15
    const int b    = blockIdx.x / OD;
    const int i    = blockIdx.x - b * OD;

    for (int t = tid; t < NGRP * IJB; t += 512) acc[t] = 0.f;
    __syncthreads();

    float miv[4] = {0.f, 0.f, 0.f, 0.f};   // static-indexed after unroll -> VGPRs
    if (lg < OWI) {
        const int wbase = 5 * lg - 2;
        const float* xb = x + (size_t)b * SPAT + i * 5 * HWSZ;
        const float* vb = vols + i * 5 * HWSZ;
        const float* wb = Wexp + i * 5 * WEXP_D + 5 * lg;
        float* accg = acc + g * IJB + lg;

        const int start = 20 * g;
        const int end   = (start + 20 < NROWS) ? start + 20 : NROWS;

        int rr = start;
        for (; rr + 3 < end; rr += 4) {
            float s[4];
            #pragma unroll
            for (int u = 0; u < 4; ++u) {
                const int row = rr + u;
                const int p = row / HH;
                const int h = row - p * HH;
                const float* xrow = xb + p * HWSZ + h * WW;
                const float* vrow = vb + p * HWSZ + h * WW;
                const float* wrow = wb + p * WEXP_D + (h + 1) * 130;
                float sv = 0.f;
                float mv = miv[u];
                #pragma unroll
                for (int r = 0; r < 5; ++r) {
                    const int w = wbase + r;
                    if ((unsigned)w < (unsigned)WW) {
                        const float xv = xrow[w];
                        sv = fmaf(xv, wrow[r], sv);
                        mv = fmaf(xv, vrow[w], mv);
                    }
                }
                miv[u] = mv;
                s[u] = sv;
            }
            #pragma unroll
            for (int u = 0; u < 4; ++u) {
                const int row = rr + u;
                const int p = row / HH;
                const int h = row - p * HH;
                accg[((h + 1) / 5) * OWI] += s[u];    // single-owner RMW
            }
        }
        for (; rr < end; ++rr) {                      // tail (group 15 only)
            const int p = rr / HH;
            const int h = rr - p * HH;
            const float* xrow = xb + p * HWSZ + h * WW;
            const float* vrow = vb + p * HWSZ + h * WW;
            const float* wrow = wb + p * WEXP_D + (h + 1) * 130;
            float sv = 0.f;
            #pragma unroll
            for (int r = 0; r < 5; ++r) {
                const int w = wbase + r;
                if ((unsigned)w < (unsigned)WW) {
                    const float xv = xrow[w];
                    sv     = fmaf(xv, wrow[r], sv);
                    miv[0] = fmaf(xv, vrow[w], miv[0]);
                }
            }
            accg[((h + 1) / 5) * OWI] += sv;
        }
    }
    float mi = (miv[0] + miv[1]) + (miv[2] + miv[3]);
    #pragma unroll
    for (int s2 = 32; s2; s2 >>= 1) mi += __shfl_down(mi, s2, 64);
    if (lane == 0) redmi[wv] = mi;
    __syncthreads();

    float mo = 0.f;
    if (tid < IJB) {
        float v = 0.f;
        #pragma unroll
        for (int w2 = 0; w2 < NGRP; ++w2) v += acc[w2 * IJB + tid];
        const int blk = i * IJB + tid;
        const float y = fmaxf(v + bias[blk], 0.f);
        y_small[(size_t)b * NBLK + blk] = y;
        mo = y * lv[blk];
    }
    #pragma unroll
    for (int s2 = 32; s2; s2 >>= 1) mo += __shfl_down(mo, s2, 64);
    if (lane == 0) redmo[wv] = mo;
    __syncthreads();
    if (tid == 0) {
        float tmi = 0.f, tmo = 0.f;
        #pragma unroll
        for (int w2 = 0; w2 < 8; ++w2) { tmi += redmi[w2]; tmo += redmo[w2]; }
        atomicAdd(mass_in  + b, (double)tmi);
        atomicAdd(mass_out + b, (double)tmo);
    }
}

// ---------------------------------------------------------------------------
// scale[b] = mass_in/mass_out (f64 divide once per batch)
// ---------------------------------------------------------------------------
__global__ void scale_kernel(const double* __restrict__ mi,
                             const double* __restrict__ mo,
                             float* __restrict__ s) {
    int t = threadIdx.x;
    if (t < BATCH) s[t] = (float)(mi[t] / mo[t]);
}

// ---------------------------------------------------------------------------
// out: flat float4 writer over batch-pairs. The pair's y (2x1014, pre-scaled)
// is staged in LDS so the per-element gather hits LDS banks, not the L1/TA.
// Nontemporal stores keep the 122 MB stream out of L2's way.
// ---------------------------------------------------------------------------
__global__ __launch_bounds__(256)
void out_kernel(const float* __restrict__ y, const unsigned short* __restrict__ tbl,
                const float* __restrict__ land, const float* __restrict__ scale,
                f32x4* __restrict__ out) {
    __shared__ float ylds[2 * NBLK];                  // 8112 B
    const unsigned PAIR4 = (2u * SPAT) / 4u;          // 59535 float4 per pair
    const unsigned CH    = 3721u;                     // ceil(59535/16)
    const unsigned b2    = blockIdx.x >> 4;           // 0..127
    const unsigned chunk = blockIdx.x & 15u;
    const unsigned begin = chunk * CH;
    const unsigned end   = (begin + CH < PAIR4) ? begin + CH : PAIR4;
    const float s0 = scale[2 * b2], s1 = scale[2 * b2 + 1];
    const float* yb = y + (size_t)(2 * b2) * NBLK;
    for (int t = threadIdx.x; t < 2 * NBLK; t += 256)
        ylds[t] = yb[t] * (t < NBLK ? s0 : s1);
    __syncthreads();

    const unsigned base4 = b2 * PAIR4;
    for (unsigned t = begin + threadIdx.x; t < end; t += 256) {
        const unsigned e0 = t * 4u;
        float o[4];
        #pragma unroll
        for (int up = 0; up < 2; ++up) {   // elem pairs never straddle SPAT (parity)
            const unsigned e  = e0 + 2u * up;
            const unsigned bo = e >= (unsigned)SPAT;
            const unsigned r  = e - (bo ? (unsigned)SPAT : 0u);
            const unsigned tt = *reinterpret_cast<const unsigned*>(tbl + r); // r even
            const float2   l2 = *reinterpret_cast<const float2*>(land + r);
            const unsigned yo = bo ? (unsigned)NBLK : 0u;
            o[2 * up]     = ylds[yo + (tt & 0xFFFFu)] * l2.x;
            o[2 * up + 1] = ylds[yo + (tt >> 16)]     * l2.y;
        }
        f32x4 v;
        v.x = o[0]; v.y = o[1]; v.z = o[2]; v.w = o[3];
        __builtin_nontemporal_store(v, &out[base4 + t]);
    }
}

// ---------------------------------------------------------------------------
extern "C" void kernel_launch(void* const* d_in, const int* in_sizes, int n_in,
                              void* d_out, int out_size, void* d_ws, size_t ws_size,
                              hipStream_t stream) {
    const float* x    = (const float*)d_in[0];
    const float* land = (const float*)d_in[1];
    const float* vols = (const float*)d_in[2];
    const float* Wt   = (const float*)d_in[3];
    const float* bias = (const float*)d_in[4];

    char* ws = (char*)d_ws;
    double*         mass_in  = (double*)(ws);                 // 2048 B
    double*         mass_out = (double*)(ws + 2048);          // 2048 B
    float*          scale    = (float*) (ws + 4096);          // 1024 B
    float*          Wexp     = (float*) (ws + 5120);          // 507000 B
    float*          lv       = (float*) (ws + 512120);        // 4056 B
    unsigned short* tbl      = (unsigned short*)(ws + 516176);// 238140 B
    float*          y_small  = (float*) (ws + 754320);        // 1038336 B

    (void)hipMemsetAsync(ws, 0, 4096, stream);   // zero mass accumulators

    prep_kernel<<<(NWEXP + NBLK + SPAT + 255) / 256, 256, 0, stream>>>(
        Wt, land, vols, Wexp, lv, tbl);

    conv_kernel<<<BATCH * OD, 512, 0, stream>>>(
        x, vols, Wexp, lv, bias, y_small, mass_in, mass_out);

    scale_kernel<<<1, 256, 0, stream>>>(mass_in, mass_out, scale);

    out_kernel<<<128 * 16, 256, 0, stream>>>(
        y_small, tbl, land, scale, (f32x4*)d_out);
}